// Round 1
// baseline (7432.656 us; speedup 1.0000x reference)
//
#include <hip/hip_runtime.h>
#include <math.h>

typedef _Float16 f16;
typedef _Float16 f16x8 __attribute__((ext_vector_type(8)));
typedef _Float16 f16x4 __attribute__((ext_vector_type(4)));
typedef float floatx4 __attribute__((ext_vector_type(4)));

#define BATCH 256
#define SEQ 64
#define DMODEL 1024
#define NHEAD 16
#define HDIM 64
#define VOCAB 64
#define DFF 4096
#define NLAYER 8
#define MS (BATCH*SEQ)   // 16384 rows

__device__ __forceinline__ floatx4 mfma16(f16x8 a, f16x8 b, floatx4 c) {
    return __builtin_amdgcn_mfma_f32_16x16x32_f16(a, b, c, 0, 0, 0);
}

__device__ __forceinline__ float gelu_f(float x) {
    return 0.5f * x * (1.f + erff(x * 0.70710678118654752f));
}

// ---------------- embed: h = tok[x] + step_embed[step]; also emit f16 copy ----
__global__ __launch_bounds__(256) void embed_k(const int* __restrict__ x, const int* __restrict__ step,
                                               const float* __restrict__ tok, const float* __restrict__ se,
                                               float* __restrict__ h, f16* __restrict__ hb) {
    int row = blockIdx.x;
    int t = threadIdx.x;
    int id = x[row];
    int si = min(max(step[0], 0), 63);
    float4 a = ((const float4*)(tok + (size_t)id * DMODEL))[t];
    float4 b = ((const float4*)(se + (size_t)si * DMODEL))[t];
    float4 o;
    o.x = a.x + b.x; o.y = a.y + b.y; o.z = a.z + b.z; o.w = a.w + b.w;
    ((float4*)(h + (size_t)row * DMODEL))[t] = o;
    f16x4 hv; hv[0] = (f16)o.x; hv[1] = (f16)o.y; hv[2] = (f16)o.z; hv[3] = (f16)o.w;
    ((f16x4*)(hb + (size_t)row * DMODEL))[t] = hv;
}

// ---------------- fp32 -> f16 convert ----------------------------------------
__global__ __launch_bounds__(256) void cvt_k(const float* __restrict__ src, f16* __restrict__ dst, int n4) {
    int i = blockIdx.x * 256 + threadIdx.x;
    if (i < n4) {
        float4 v = ((const float4*)src)[i];
        f16x4 o; o[0] = (f16)v.x; o[1] = (f16)v.y; o[2] = (f16)v.z; o[3] = (f16)v.w;
        ((f16x4*)dst)[i] = o;
    }
}

// ---------------- GEMM: C[M,N] = A[M,K] @ Bw[N,K]^T (+bias, +mode epilogue) ---
// MODE 0: store f16 (bias)    MODE 1: store f16 (bias+gelu)   MODE 2: h += acc+bias (fp32)
template<int MODE>
__global__ __launch_bounds__(256) void gemm_k(const f16* __restrict__ A, const f16* __restrict__ Bw,
                                              const float* __restrict__ bias,
                                              f16* __restrict__ Cb, float* __restrict__ Hacc,
                                              int M, int N, int K) {
    __shared__ f16 smem[16384];      // As 128x64 | Bs 128x64 ; reused as Cs 128x128
    f16* As = smem;
    f16* Bs = smem + 8192;

    const int tid = threadIdx.x;
    const int lane = tid & 63;
    const int wave = tid >> 6;
    const int wm = wave >> 1, wn = wave & 1;
    const int lr = lane & 15, lg = lane >> 4;
    const int m0 = blockIdx.y * 128, n0 = blockIdx.x * 128;

    floatx4 acc[4][4] = {};

    const int srow = tid >> 3;          // 0..31
    const int scol = (tid & 7) * 8;     // 0..56
    const f16* Ag0 = A + (size_t)(m0 + srow) * K + scol;
    const f16* Bg0 = Bw + (size_t)(n0 + srow) * K + scol;
    f16* Asw = As + srow * 64 + scol;
    f16* Bsw = Bs + srow * 64 + scol;

    for (int kt = 0; kt < K; kt += 64) {
        f16x8 av[4], bv[4];
#pragma unroll
        for (int i = 0; i < 4; ++i) av[i] = *(const f16x8*)(Ag0 + kt + (size_t)i * 32 * K);
#pragma unroll
        for (int i = 0; i < 4; ++i) bv[i] = *(const f16x8*)(Bg0 + kt + (size_t)i * 32 * K);
#pragma unroll
        for (int i = 0; i < 4; ++i) *(f16x8*)(Asw + i * 2048) = av[i];
#pragma unroll
        for (int i = 0; i < 4; ++i) *(f16x8*)(Bsw + i * 2048) = bv[i];
        __syncthreads();
#pragma unroll
        for (int kk = 0; kk < 64; kk += 32) {
            f16x8 af[4], bf[4];
            const f16* Ar = As + (wm * 64 + lr) * 64 + kk + lg * 8;
            const f16* Br = Bs + (wn * 64 + lr) * 64 + kk + lg * 8;
#pragma unroll
            for (int i = 0; i < 4; ++i) af[i] = *(const f16x8*)(Ar + i * 16 * 64);
#pragma unroll
            for (int i = 0; i < 4; ++i) bf[i] = *(const f16x8*)(Br + i * 16 * 64);
#pragma unroll
            for (int mi = 0; mi < 4; ++mi)
#pragma unroll
                for (int ni = 0; ni < 4; ++ni)
                    acc[mi][ni] = mfma16(af[mi], bf[ni], acc[mi][ni]);
        }
        __syncthreads();
    }

    if (MODE == 2) {
#pragma unroll
        for (int ni = 0; ni < 4; ++ni) {
            int cc = n0 + wn * 64 + ni * 16 + lr;
            float bvl = bias[cc];
#pragma unroll
            for (int mi = 0; mi < 4; ++mi)
#pragma unroll
                for (int j = 0; j < 4; ++j) {
                    int rr = m0 + wm * 64 + mi * 16 + lg * 4 + j;
                    float* p = Hacc + (size_t)rr * N + cc;
                    *p += acc[mi][ni][j] + bvl;
                }
        }
    } else {
        f16* Cs = smem;   // 128x128
#pragma unroll
        for (int ni = 0; ni < 4; ++ni) {
            int ccl = wn * 64 + ni * 16 + lr;
            float bvl = bias[n0 + ccl];
#pragma unroll
            for (int mi = 0; mi < 4; ++mi)
#pragma unroll
                for (int j = 0; j < 4; ++j) {
                    float v = acc[mi][ni][j] + bvl;
                    if (MODE == 1) v = gelu_f(v);
                    Cs[(wm * 64 + mi * 16 + lg * 4 + j) * 128 + ccl] = (f16)v;
                }
        }
        __syncthreads();
        const int sr = tid >> 1, sc = (tid & 1) * 64;
#pragma unroll
        for (int i = 0; i < 8; ++i) {
            f16x8 v = *(const f16x8*)&Cs[sr * 128 + sc + i * 8];
            *(f16x8*)(Cb + (size_t)(m0 + sr) * N + n0 + sc + i * 8) = v;
        }
    }
}

// ---------------- attention: one wave per (b,h) -------------------------------
__global__ __launch_bounds__(64) void attn_k(const f16* __restrict__ qkv, const float* __restrict__ rb,
                                             f16* __restrict__ ctx) {
    const int hh = blockIdx.x;
    const int bb = blockIdx.y;
    const int lane = threadIdx.x;
    __shared__ float rbs[128];
    __shared__ f16 Vt[64][72];
    __shared__ f16 Pl[64][72];

    for (int i = lane; i < 127; i += 64) rbs[i] = rb[i];

    // stage V transposed: Vt[hd][s]
    const f16* vrow = qkv + (size_t)(bb * 64 + lane) * 3072 + 2048 + hh * 64;
#pragma unroll
    for (int i = 0; i < 8; ++i) {
        f16x8 v = *(const f16x8*)(vrow + i * 8);
#pragma unroll
        for (int j = 0; j < 8; ++j) Vt[i * 8 + j][lane] = v[j];
    }
    __syncthreads();

    const int lr = lane & 15, lg = lane >> 4;
    floatx4 sacc[4][4] = {};
    const f16* qbase = qkv + (size_t)(bb * 64) * 3072 + hh * 64;
#pragma unroll
    for (int kk = 0; kk < 64; kk += 32) {
        f16x8 qa[4], kb[4];
#pragma unroll
        for (int mf = 0; mf < 4; ++mf)
            qa[mf] = *(const f16x8*)(qbase + (size_t)(mf * 16 + lr) * 3072 + kk + lg * 8);
#pragma unroll
        for (int nf = 0; nf < 4; ++nf)
            kb[nf] = *(const f16x8*)(qbase + 1024 + (size_t)(nf * 16 + lr) * 3072 + kk + lg * 8);
#pragma unroll
        for (int mf = 0; mf < 4; ++mf)
#pragma unroll
            for (int nf = 0; nf < 4; ++nf)
                sacc[mf][nf] = mfma16(qa[mf], kb[nf], sacc[mf][nf]);
    }

    // softmax (rows spread over 16-lane groups; shfl_xor 1/2/4/8 stays in group)
#pragma unroll
    for (int mf = 0; mf < 4; ++mf) {
#pragma unroll
        for (int j = 0; j < 4; ++j) {
            int qrow = mf * 16 + lg * 4 + j;
            float v0 = sacc[mf][0][j] * 0.125f + rbs[qrow - (0  + lr) + 63];
            float v1 = sacc[mf][1][j] * 0.125f + rbs[qrow - (16 + lr) + 63];
            float v2 = sacc[mf][2][j] * 0.125f + rbs[qrow - (32 + lr) + 63];
            float v3 = sacc[mf][3][j] * 0.125f + rbs[qrow - (48 + lr) + 63];
            float mx = fmaxf(fmaxf(v0, v1), fmaxf(v2, v3));
            for (int m = 1; m < 16; m <<= 1) mx = fmaxf(mx, __shfl_xor(mx, m));
            v0 = __expf(v0 - mx); v1 = __expf(v1 - mx); v2 = __expf(v2 - mx); v3 = __expf(v3 - mx);
            float sum = v0 + v1 + v2 + v3;
            for (int m = 1; m < 16; m <<= 1) sum += __shfl_xor(sum, m);
            float inv = 1.f / sum;
            Pl[qrow][0  + lr] = (f16)(v0 * inv);
            Pl[qrow][16 + lr] = (f16)(v1 * inv);
            Pl[qrow][32 + lr] = (f16)(v2 * inv);
            Pl[qrow][48 + lr] = (f16)(v3 * inv);
        }
    }
    __syncthreads();

    floatx4 oacc[4][4] = {};
#pragma unroll
    for (int kk = 0; kk < 64; kk += 32) {
        f16x8 pa[4], vb[4];
#pragma unroll
        for (int mf = 0; mf < 4; ++mf) pa[mf] = *(const f16x8*)&Pl[mf * 16 + lr][kk + lg * 8];
#pragma unroll
        for (int nf = 0; nf < 4; ++nf) vb[nf] = *(const f16x8*)&Vt[nf * 16 + lr][kk + lg * 8];
#pragma unroll
        for (int mf = 0; mf < 4; ++mf)
#pragma unroll
            for (int nf = 0; nf < 4; ++nf)
                oacc[mf][nf] = mfma16(pa[mf], vb[nf], oacc[mf][nf]);
    }
    __syncthreads();
    // bounce O through Pl for coalesced stores
#pragma unroll
    for (int mf = 0; mf < 4; ++mf)
#pragma unroll
        for (int nf = 0; nf < 4; ++nf)
#pragma unroll
            for (int j = 0; j < 4; ++j)
                Pl[mf * 16 + lg * 4 + j][nf * 16 + lr] = (f16)oacc[mf][nf][j];
    __syncthreads();
    f16* crow = ctx + (size_t)(bb * 64 + lane) * DMODEL + hh * 64;
#pragma unroll
    for (int i = 0; i < 8; ++i) {
        f16x8 v = *(const f16x8*)&Pl[lane][i * 8];
        *(f16x8*)(crow + i * 8) = v;
    }
}

// ---------------- LayerNorm in-place on h, optionally emit f16 copy -----------
__global__ __launch_bounds__(256) void ln_k(float* __restrict__ h, const float* __restrict__ g,
                                            const float* __restrict__ b, f16* __restrict__ hb, int emit) {
    int row = blockIdx.x;
    int t = threadIdx.x;
    float4 v = ((const float4*)(h + (size_t)row * DMODEL))[t];
    float s = v.x + v.y + v.z + v.w;
    float ss = v.x * v.x + v.y * v.y + v.z * v.z + v.w * v.w;
    for (int m = 1; m < 64; m <<= 1) { s += __shfl_xor(s, m); ss += __shfl_xor(ss, m); }
    __shared__ float red[8];
    if ((t & 63) == 0) { red[(t >> 6) * 2] = s; red[(t >> 6) * 2 + 1] = ss; }
    __syncthreads();
    s = red[0] + red[2] + red[4] + red[6];
    ss = red[1] + red[3] + red[5] + red[7];
    float mean = s * (1.f / 1024.f);
    float var = ss * (1.f / 1024.f) - mean * mean;
    float rstd = rsqrtf(var + 1e-5f);
    float4 gg = ((const float4*)g)[t];
    float4 bb = ((const float4*)b)[t];
    float4 o;
    o.x = (v.x - mean) * rstd * gg.x + bb.x;
    o.y = (v.y - mean) * rstd * gg.y + bb.y;
    o.z = (v.z - mean) * rstd * gg.z + bb.z;
    o.w = (v.w - mean) * rstd * gg.w + bb.w;
    ((float4*)(h + (size_t)row * DMODEL))[t] = o;
    if (emit) {
        f16x4 hv; hv[0] = (f16)o.x; hv[1] = (f16)o.y; hv[2] = (f16)o.z; hv[3] = (f16)o.w;
        ((f16x4*)(hb + (size_t)row * DMODEL))[t] = hv;
    }
}

// ---------------- mean over S -------------------------------------------------
__global__ __launch_bounds__(256) void pool_k(const float* __restrict__ h, float* __restrict__ pooled) {
    int b = blockIdx.x;
    int t = threadIdx.x;
    float sx = 0, sy = 0, sz = 0, sw = 0;
    for (int s = 0; s < SEQ; ++s) {
        float4 v = ((const float4*)(h + (size_t)(b * SEQ + s) * DMODEL))[t];
        sx += v.x; sy += v.y; sz += v.z; sw += v.w;
    }
    float4 o; o.x = sx * (1.f / 64.f); o.y = sy * (1.f / 64.f); o.z = sz * (1.f / 64.f); o.w = sw * (1.f / 64.f);
    ((float4*)(pooled + (size_t)b * DMODEL))[t] = o;
}

// ---------------- policy / value heads ---------------------------------------
__global__ __launch_bounds__(64) void head_k(const float* __restrict__ pooled, const float* __restrict__ pw,
                                             const float* __restrict__ pb, const float* __restrict__ vw,
                                             const float* __restrict__ vb, float* __restrict__ out) {
    int b = blockIdx.x;
    int lane = threadIdx.x;
    const float* pr = pooled + (size_t)b * DMODEL;
    const float* wr = pw + (size_t)lane * DMODEL;
    float accp = 0.f;
    for (int d = 0; d < DMODEL; d += 4) {
        float4 x = *(const float4*)(pr + d);
        float4 w = *(const float4*)(wr + d);
        accp += x.x * w.x + x.y * w.y + x.z * w.z + x.w * w.w;
    }
    float accv = 0.f;
    for (int d = lane * 4; d < DMODEL; d += 256) {
        float4 x = *(const float4*)(pr + d);
        float4 w = *(const float4*)(vw + d);
        accv += x.x * w.x + x.y * w.y + x.z * w.z + x.w * w.w;
    }
    for (int m = 1; m < 64; m <<= 1) accv += __shfl_xor(accv, m);
    out[b * VOCAB + lane] = accp + pb[lane];
    if (lane == 0) out[BATCH * VOCAB + b] = accv + vb[0];
}

extern "C" void kernel_launch(void* const* d_in, const int* in_sizes, int n_in,
                              void* d_out, int out_size, void* d_ws, size_t ws_size,
                              hipStream_t stream) {
    const int*   x      = (const int*)d_in[0];
    const int*   step   = (const int*)d_in[1];
    const float* tok    = (const float*)d_in[2];
    const float* se     = (const float*)d_in[3];
    const float* qkv_w  = (const float*)d_in[4];
    const float* qkv_b  = (const float*)d_in[5];
    const float* out_w  = (const float*)d_in[6];
    const float* out_b  = (const float*)d_in[7];
    const float* relb   = (const float*)d_in[8];
    const float* w1     = (const float*)d_in[9];
    const float* b1     = (const float*)d_in[10];
    const float* w2     = (const float*)d_in[11];
    const float* b2     = (const float*)d_in[12];
    const float* ln1g   = (const float*)d_in[13];
    const float* ln1b   = (const float*)d_in[14];
    const float* ln2g   = (const float*)d_in[15];
    const float* ln2b   = (const float*)d_in[16];
    const float* lnog   = (const float*)d_in[17];
    const float* lnob   = (const float*)d_in[18];
    const float* pw     = (const float*)d_in[19];
    const float* pb     = (const float*)d_in[20];
    const float* vw     = (const float*)d_in[21];
    const float* vb     = (const float*)d_in[22];

    float* out = (float*)d_out;
    float* h = out + BATCH * VOCAB + BATCH;       // h region: [16384,1024] fp32

    char* ws = (char*)d_ws;
    f16* hb     = (f16*)(ws);                                  // 33,554,432 B
    f16* uni    = (f16*)(ws + 33554432);                       // qkv16 / ffn16 union: 134,217,728 B
    f16* qkv16  = uni;
    f16* ffn16  = uni;
    f16* ctx16  = (f16*)(ws + 167772160);                      // 33,554,432 B
    f16* wqb    = (f16*)(ws + 201326592);                      // 6,291,456 B
    f16* wob    = (f16*)(ws + 207618048);                      // 2,097,152 B
    f16* w1b    = (f16*)(ws + 209715200);                      // 8,388,608 B
    f16* w2b    = (f16*)(ws + 218103808);                      // 8,388,608 B
    float* pooled = (float*)(ws + 226492416);                  // 1,048,576 B

    embed_k<<<MS, 256, 0, stream>>>(x, step, tok, se, h, hb);

    for (int l = 0; l < NLAYER; ++l) {
        cvt_k<<<3072, 256, 0, stream>>>(qkv_w + (size_t)l * 3145728, wqb, 786432);
        cvt_k<<<1024, 256, 0, stream>>>(out_w + (size_t)l * 1048576, wob, 262144);
        cvt_k<<<4096, 256, 0, stream>>>(w1 + (size_t)l * 4194304, w1b, 1048576);
        cvt_k<<<4096, 256, 0, stream>>>(w2 + (size_t)l * 4194304, w2b, 1048576);

        gemm_k<0><<<dim3(24, 128), 256, 0, stream>>>(hb, wqb, qkv_b + l * 3072, qkv16, nullptr, MS, 3072, 1024);
        attn_k<<<dim3(NHEAD, BATCH), 64, 0, stream>>>(qkv16, relb + l * 127, ctx16);
        gemm_k<2><<<dim3(8, 128), 256, 0, stream>>>(ctx16, wob, out_b + l * 1024, nullptr, h, MS, 1024, 1024);
        ln_k<<<MS, 256, 0, stream>>>(h, ln1g + l * 1024, ln1b + l * 1024, hb, 1);
        gemm_k<1><<<dim3(32, 128), 256, 0, stream>>>(hb, w1b, b1 + l * 4096, ffn16, nullptr, MS, 4096, 1024);
        gemm_k<2><<<dim3(8, 128), 256, 0, stream>>>(ffn16, w2b, b2 + l * 1024, nullptr, h, MS, 1024, 4096);
        ln_k<<<MS, 256, 0, stream>>>(h, ln2g + l * 1024, ln2b + l * 1024, hb, 1);
    }

    ln_k<<<MS, 256, 0, stream>>>(h, lnog, lnob, hb, 0);
    pool_k<<<BATCH, 256, 0, stream>>>(h, pooled);
    head_k<<<BATCH, 64, 0, stream>>>(pooled, pw, pb, vw, vb, out);
}

// Round 2
// 6460.812 us; speedup vs baseline: 1.1504x; 1.1504x over previous
//
#include <hip/hip_runtime.h>
#include <math.h>

typedef _Float16 f16;
typedef _Float16 f16x8 __attribute__((ext_vector_type(8)));
typedef _Float16 f16x4 __attribute__((ext_vector_type(4)));
typedef float floatx4 __attribute__((ext_vector_type(4)));

#define BATCH 256
#define SEQ 64
#define DMODEL 1024
#define NHEAD 16
#define HDIM 64
#define VOCAB 64
#define DFF 4096
#define NLAYER 8
#define MS (BATCH*SEQ)   // 16384 rows

#define GPTR(p) ((const __attribute__((address_space(1))) void*)(p))
#define LPTR(p) ((__attribute__((address_space(3))) void*)(p))

__device__ __forceinline__ floatx4 mfma16(f16x8 a, f16x8 b, floatx4 c) {
    return __builtin_amdgcn_mfma_f32_16x16x32_f16(a, b, c, 0, 0, 0);
}

__device__ __forceinline__ float gelu_f(float x) {
    return 0.5f * x * (1.f + erff(x * 0.70710678118654752f));
}

// ---------------- embed: h = tok[x] + step_embed[step]; also emit f16 copy ----
__global__ __launch_bounds__(256) void embed_k(const int* __restrict__ x, const int* __restrict__ step,
                                               const float* __restrict__ tok, const float* __restrict__ se,
                                               float* __restrict__ h, f16* __restrict__ hb) {
    int row = blockIdx.x;
    int t = threadIdx.x;
    int id = x[row];
    int si = min(max(step[0], 0), 63);
    float4 a = ((const float4*)(tok + (size_t)id * DMODEL))[t];
    float4 b = ((const float4*)(se + (size_t)si * DMODEL))[t];
    float4 o;
    o.x = a.x + b.x; o.y = a.y + b.y; o.z = a.z + b.z; o.w = a.w + b.w;
    ((float4*)(h + (size_t)row * DMODEL))[t] = o;
    f16x4 hv; hv[0] = (f16)o.x; hv[1] = (f16)o.y; hv[2] = (f16)o.z; hv[3] = (f16)o.w;
    ((f16x4*)(hb + (size_t)row * DMODEL))[t] = hv;
}

// ---------------- fp32 -> f16 convert ----------------------------------------
__global__ __launch_bounds__(256) void cvt_k(const float* __restrict__ src, f16* __restrict__ dst, int n4) {
    int i = blockIdx.x * 256 + threadIdx.x;
    if (i < n4) {
        float4 v = ((const float4*)src)[i];
        f16x4 o; o[0] = (f16)v.x; o[1] = (f16)v.y; o[2] = (f16)v.z; o[3] = (f16)v.w;
        ((f16x4*)dst)[i] = o;
    }
}

// ---------------- GEMM: C[M,N] = A[M,K] @ Bw[N,K]^T (+bias, +mode epilogue) ---
// m97 structure: 128x128 tile, BK=64, global_load_lds(16B), T2 XOR-swizzle.
// LDS layout: physical (row, cb) holds logical col-block cb ^ (row&7).
// MODE 0: store f16 (bias)    MODE 1: store f16 (bias+gelu)   MODE 2: h += acc+bias (fp32)
template<int MODE>
__global__ __launch_bounds__(256) void gemm_k(const f16* __restrict__ A, const f16* __restrict__ Bw,
                                              const float* __restrict__ bias,
                                              f16* __restrict__ Cb, float* __restrict__ Hacc,
                                              int M, int N, int K) {
    __shared__ f16 smem[16384];      // As 128x64 | Bs 128x64 ; reused as Cs 128x128
    f16* As = smem;
    f16* Bs = smem + 8192;

    const int tid = threadIdx.x;
    const int lane = tid & 63;
    const int wave = tid >> 6;
    const int wm = wave >> 1, wn = wave & 1;
    const int lr = lane & 15, lg = lane >> 4;

    // ---- bijective XCD-aware block swizzle (nwg % 8 == 0 for all our grids) --
    const unsigned nx = gridDim.x;
    const unsigned nwg = nx * gridDim.y;
    unsigned flat = blockIdx.y * nx + blockIdx.x;
    flat = (flat & 7u) * (nwg >> 3) + (flat >> 3);
    const int m0 = (int)(flat / nx) * 128;
    const int n0 = (int)(flat % nx) * 128;

    floatx4 acc[4][4] = {};

    // ---- staging geometry: call c covers rows c*32..c*32+31 of the tile ------
    // lane covers physical (row = wave*8 + lane/8 + c*32, cb = lane&7).
    // source col-block = cb ^ (row&7); row&7 is constant across calls.
    const int prow = wave * 8 + (lane >> 3);
    const int scb = (lane & 7) ^ (prow & 7);
    const f16* Asrc = A + (size_t)(m0 + prow) * K + scb * 8;
    const f16* Bsrc = Bw + (size_t)(n0 + prow) * K + scb * 8;
    f16* AsW = As + wave * 512;     // wave-uniform LDS base (HW adds lane*16B)
    f16* BsW = Bs + wave * 512;

    const int sa = lr & 7;          // frag row & 7 (r = w*64+i*16+lr)

    for (int kt = 0; kt < K; kt += 64) {
#pragma unroll
        for (int c = 0; c < 4; ++c)
            __builtin_amdgcn_global_load_lds(GPTR(Asrc + kt + (size_t)c * 32 * K),
                                             LPTR(AsW + c * 2048), 16, 0, 0);
#pragma unroll
        for (int c = 0; c < 4; ++c)
            __builtin_amdgcn_global_load_lds(GPTR(Bsrc + kt + (size_t)c * 32 * K),
                                             LPTR(BsW + c * 2048), 16, 0, 0);
        __syncthreads();
#pragma unroll
        for (int kk = 0; kk < 64; kk += 32) {
            f16x8 af[4], bf[4];
            const int kb = (kk >> 3) + lg;
            const int pcb = (kb ^ sa) * 8;
#pragma unroll
            for (int i = 0; i < 4; ++i)
                af[i] = *(const f16x8*)(As + (wm * 64 + i * 16 + lr) * 64 + pcb);
#pragma unroll
            for (int i = 0; i < 4; ++i)
                bf[i] = *(const f16x8*)(Bs + (wn * 64 + i * 16 + lr) * 64 + pcb);
#pragma unroll
            for (int mi = 0; mi < 4; ++mi)
#pragma unroll
                for (int ni = 0; ni < 4; ++ni)
                    acc[mi][ni] = mfma16(af[mi], bf[ni], acc[mi][ni]);
        }
        __syncthreads();
    }

    if (MODE == 2) {
#pragma unroll
        for (int ni = 0; ni < 4; ++ni) {
            int cc = n0 + wn * 64 + ni * 16 + lr;
            float bvl = bias[cc];
#pragma unroll
            for (int mi = 0; mi < 4; ++mi)
#pragma unroll
                for (int j = 0; j < 4; ++j) {
                    int rr = m0 + wm * 64 + mi * 16 + lg * 4 + j;
                    float* p = Hacc + (size_t)rr * N + cc;
                    *p += acc[mi][ni][j] + bvl;
                }
        }
    } else {
        f16* Cs = smem;   // 128x128
#pragma unroll
        for (int ni = 0; ni < 4; ++ni) {
            int ccl = wn * 64 + ni * 16 + lr;
            float bvl = bias[n0 + ccl];
#pragma unroll
            for (int mi = 0; mi < 4; ++mi)
#pragma unroll
                for (int j = 0; j < 4; ++j) {
                    float v = acc[mi][ni][j] + bvl;
                    if (MODE == 1) v = gelu_f(v);
                    Cs[(wm * 64 + mi * 16 + lg * 4 + j) * 128 + ccl] = (f16)v;
                }
        }
        __syncthreads();
        const int sr = tid >> 1, sc = (tid & 1) * 64;
#pragma unroll
        for (int i = 0; i < 8; ++i) {
            f16x8 v = *(const f16x8*)&Cs[sr * 128 + sc + i * 8];
            *(f16x8*)(Cb + (size_t)(m0 + sr) * N + n0 + sc + i * 8) = v;
        }
    }
}

// ---------------- attention: one wave per (b,h) -------------------------------
__global__ __launch_bounds__(64) void attn_k(const f16* __restrict__ qkv, const float* __restrict__ rb,
                                             f16* __restrict__ ctx) {
    const int hh = blockIdx.x;
    const int bb = blockIdx.y;
    const int lane = threadIdx.x;
    __shared__ float rbs[128];
    __shared__ f16 Vt[64][72];
    __shared__ f16 Pl[64][72];

    for (int i = lane; i < 127; i += 64) rbs[i] = rb[i];

    // stage V transposed: Vt[hd][s]
    const f16* vrow = qkv + (size_t)(bb * 64 + lane) * 3072 + 2048 + hh * 64;
#pragma unroll
    for (int i = 0; i < 8; ++i) {
        f16x8 v = *(const f16x8*)(vrow + i * 8);
#pragma unroll
        for (int j = 0; j < 8; ++j) Vt[i * 8 + j][lane] = v[j];
    }
    __syncthreads();

    const int lr = lane & 15, lg = lane >> 4;
    floatx4 sacc[4][4] = {};
    const f16* qbase = qkv + (size_t)(bb * 64) * 3072 + hh * 64;
#pragma unroll
    for (int kk = 0; kk < 64; kk += 32) {
        f16x8 qa[4], kb[4];
#pragma unroll
        for (int mf = 0; mf < 4; ++mf)
            qa[mf] = *(const f16x8*)(qbase + (size_t)(mf * 16 + lr) * 3072 + kk + lg * 8);
#pragma unroll
        for (int nf = 0; nf < 4; ++nf)
            kb[nf] = *(const f16x8*)(qbase + 1024 + (size_t)(nf * 16 + lr) * 3072 + kk + lg * 8);
#pragma unroll
        for (int mf = 0; mf < 4; ++mf)
#pragma unroll
            for (int nf = 0; nf < 4; ++nf)
                sacc[mf][nf] = mfma16(qa[mf], kb[nf], sacc[mf][nf]);
    }

    // softmax (rows spread over 16-lane groups; shfl_xor 1/2/4/8 stays in group)
#pragma unroll
    for (int mf = 0; mf < 4; ++mf) {
#pragma unroll
        for (int j = 0; j < 4; ++j) {
            int qrow = mf * 16 + lg * 4 + j;
            float v0 = sacc[mf][0][j] * 0.125f + rbs[qrow - (0  + lr) + 63];
            float v1 = sacc[mf][1][j] * 0.125f + rbs[qrow - (16 + lr) + 63];
            float v2 = sacc[mf][2][j] * 0.125f + rbs[qrow - (32 + lr) + 63];
            float v3 = sacc[mf][3][j] * 0.125f + rbs[qrow - (48 + lr) + 63];
            float mx = fmaxf(fmaxf(v0, v1), fmaxf(v2, v3));
            for (int m = 1; m < 16; m <<= 1) mx = fmaxf(mx, __shfl_xor(mx, m));
            v0 = __expf(v0 - mx); v1 = __expf(v1 - mx); v2 = __expf(v2 - mx); v3 = __expf(v3 - mx);
            float sum = v0 + v1 + v2 + v3;
            for (int m = 1; m < 16; m <<= 1) sum += __shfl_xor(sum, m);
            float inv = 1.f / sum;
            Pl[qrow][0  + lr] = (f16)(v0 * inv);
            Pl[qrow][16 + lr] = (f16)(v1 * inv);
            Pl[qrow][32 + lr] = (f16)(v2 * inv);
            Pl[qrow][48 + lr] = (f16)(v3 * inv);
        }
    }
    __syncthreads();

    floatx4 oacc[4][4] = {};
#pragma unroll
    for (int kk = 0; kk < 64; kk += 32) {
        f16x8 pa[4], vb[4];
#pragma unroll
        for (int mf = 0; mf < 4; ++mf) pa[mf] = *(const f16x8*)&Pl[mf * 16 + lr][kk + lg * 8];
#pragma unroll
        for (int nf = 0; nf < 4; ++nf) vb[nf] = *(const f16x8*)&Vt[nf * 16 + lr][kk + lg * 8];
#pragma unroll
        for (int mf = 0; mf < 4; ++mf)
#pragma unroll
            for (int nf = 0; nf < 4; ++nf)
                oacc[mf][nf] = mfma16(pa[mf], vb[nf], oacc[mf][nf]);
    }
    __syncthreads();
    // bounce O through Pl for coalesced stores
#pragma unroll
    for (int mf = 0; mf < 4; ++mf)
#pragma unroll
        for (int nf = 0; nf < 4; ++nf)
#pragma unroll
            for (int j = 0; j < 4; ++j)
                Pl[mf * 16 + lg * 4 + j][nf * 16 + lr] = (f16)oacc[mf][nf][j];
    __syncthreads();
    f16* crow = ctx + (size_t)(bb * 64 + lane) * DMODEL + hh * 64;
#pragma unroll
    for (int i = 0; i < 8; ++i) {
        f16x8 v = *(const f16x8*)&Pl[lane][i * 8];
        *(f16x8*)(crow + i * 8) = v;
    }
}

// ---------------- LayerNorm in-place on h, optionally emit f16 copy -----------
__global__ __launch_bounds__(256) void ln_k(float* __restrict__ h, const float* __restrict__ g,
                                            const float* __restrict__ b, f16* __restrict__ hb, int emit) {
    int row = blockIdx.x;
    int t = threadIdx.x;
    float4 v = ((const float4*)(h + (size_t)row * DMODEL))[t];
    float s = v.x + v.y + v.z + v.w;
    float ss = v.x * v.x + v.y * v.y + v.z * v.z + v.w * v.w;
    for (int m = 1; m < 64; m <<= 1) { s += __shfl_xor(s, m); ss += __shfl_xor(ss, m); }
    __shared__ float red[8];
    if ((t & 63) == 0) { red[(t >> 6) * 2] = s; red[(t >> 6) * 2 + 1] = ss; }
    __syncthreads();
    s = red[0] + red[2] + red[4] + red[6];
    ss = red[1] + red[3] + red[5] + red[7];
    float mean = s * (1.f / 1024.f);
    float var = ss * (1.f / 1024.f) - mean * mean;
    float rstd = rsqrtf(var + 1e-5f);
    float4 gg = ((const float4*)g)[t];
    float4 bb = ((const float4*)b)[t];
    float4 o;
    o.x = (v.x - mean) * rstd * gg.x + bb.x;
    o.y = (v.y - mean) * rstd * gg.y + bb.y;
    o.z = (v.z - mean) * rstd * gg.z + bb.z;
    o.w = (v.w - mean) * rstd * gg.w + bb.w;
    ((float4*)(h + (size_t)row * DMODEL))[t] = o;
    if (emit) {
        f16x4 hv; hv[0] = (f16)o.x; hv[1] = (f16)o.y; hv[2] = (f16)o.z; hv[3] = (f16)o.w;
        ((f16x4*)(hb + (size_t)row * DMODEL))[t] = hv;
    }
}

// ---------------- mean over S -------------------------------------------------
__global__ __launch_bounds__(256) void pool_k(const float* __restrict__ h, float* __restrict__ pooled) {
    int b = blockIdx.x;
    int t = threadIdx.x;
    float sx = 0, sy = 0, sz = 0, sw = 0;
    for (int s = 0; s < SEQ; ++s) {
        float4 v = ((const float4*)(h + (size_t)(b * SEQ + s) * DMODEL))[t];
        sx += v.x; sy += v.y; sz += v.z; sw += v.w;
    }
    float4 o; o.x = sx * (1.f / 64.f); o.y = sy * (1.f / 64.f); o.z = sz * (1.f / 64.f); o.w = sw * (1.f / 64.f);
    ((float4*)(pooled + (size_t)b * DMODEL))[t] = o;
}

// ---------------- policy / value heads ---------------------------------------
__global__ __launch_bounds__(64) void head_k(const float* __restrict__ pooled, const float* __restrict__ pw,
                                             const float* __restrict__ pb, const float* __restrict__ vw,
                                             const float* __restrict__ vb, float* __restrict__ out) {
    int b = blockIdx.x;
    int lane = threadIdx.x;
    const float* pr = pooled + (size_t)b * DMODEL;
    const float* wr = pw + (size_t)lane * DMODEL;
    float accp = 0.f;
    for (int d = 0; d < DMODEL; d += 4) {
        float4 x = *(const float4*)(pr + d);
        float4 w = *(const float4*)(wr + d);
        accp += x.x * w.x + x.y * w.y + x.z * w.z + x.w * w.w;
    }
    float accv = 0.f;
    for (int d = lane * 4; d < DMODEL; d += 256) {
        float4 x = *(const float4*)(pr + d);
        float4 w = *(const float4*)(vw + d);
        accv += x.x * w.x + x.y * w.y + x.z * w.z + x.w * w.w;
    }
    for (int m = 1; m < 64; m <<= 1) accv += __shfl_xor(accv, m);
    out[b * VOCAB + lane] = accp + pb[lane];
    if (lane == 0) out[BATCH * VOCAB + b] = accv + vb[0];
}

extern "C" void kernel_launch(void* const* d_in, const int* in_sizes, int n_in,
                              void* d_out, int out_size, void* d_ws, size_t ws_size,
                              hipStream_t stream) {
    const int*   x      = (const int*)d_in[0];
    const int*   step   = (const int*)d_in[1];
    const float* tok    = (const float*)d_in[2];
    const float* se     = (const float*)d_in[3];
    const float* qkv_w  = (const float*)d_in[4];
    const float* qkv_b  = (const float*)d_in[5];
    const float* out_w  = (const float*)d_in[6];
    const float* out_b  = (const float*)d_in[7];
    const float* relb   = (const float*)d_in[8];
    const float* w1     = (const float*)d_in[9];
    const float* b1     = (const float*)d_in[10];
    const float* w2     = (const float*)d_in[11];
    const float* b2     = (const float*)d_in[12];
    const float* ln1g   = (const float*)d_in[13];
    const float* ln1b   = (const float*)d_in[14];
    const float* ln2g   = (const float*)d_in[15];
    const float* ln2b   = (const float*)d_in[16];
    const float* lnog   = (const float*)d_in[17];
    const float* lnob   = (const float*)d_in[18];
    const float* pw     = (const float*)d_in[19];
    const float* pb     = (const float*)d_in[20];
    const float* vw     = (const float*)d_in[21];
    const float* vb     = (const float*)d_in[22];

    float* out = (float*)d_out;
    float* h = out + BATCH * VOCAB + BATCH;       // h region: [16384,1024] fp32

    char* ws = (char*)d_ws;
    f16* hb     = (f16*)(ws);                                  // 33,554,432 B
    f16* uni    = (f16*)(ws + 33554432);                       // qkv16 / ffn16 union: 134,217,728 B
    f16* qkv16  = uni;
    f16* ffn16  = uni;
    f16* ctx16  = (f16*)(ws + 167772160);                      // 33,554,432 B
    f16* wqb    = (f16*)(ws + 201326592);                      // 6,291,456 B
    f16* wob    = (f16*)(ws + 207618048);                      // 2,097,152 B
    f16* w1b    = (f16*)(ws + 209715200);                      // 8,388,608 B
    f16* w2b    = (f16*)(ws + 218103808);                      // 8,388,608 B
    float* pooled = (float*)(ws + 226492416);                  // 1,048,576 B

    embed_k<<<MS, 256, 0, stream>>>(x, step, tok, se, h, hb);

    for (int l = 0; l < NLAYER; ++l) {
        cvt_k<<<3072, 256, 0, stream>>>(qkv_w + (size_t)l * 3145728, wqb, 786432);
        cvt_k<<<1024, 256, 0, stream>>>(out_w + (size_t)l * 1048576, wob, 262144);
        cvt_k<<<4096, 256, 0, stream>>>(w1 + (size_t)l * 4194304, w1b, 1048576);
        cvt_k<<<4096, 256, 0, stream>>>(w2 + (size_t)l * 4194304, w2b, 1048576);

        gemm_k<0><<<dim3(24, 128), 256, 0, stream>>>(hb, wqb, qkv_b + l * 3072, qkv16, nullptr, MS, 3072, 1024);
        attn_k<<<dim3(NHEAD, BATCH), 64, 0, stream>>>(qkv16, relb + l * 127, ctx16);
        gemm_k<2><<<dim3(8, 128), 256, 0, stream>>>(ctx16, wob, out_b + l * 1024, nullptr, h, MS, 1024, 1024);
        ln_k<<<MS, 256, 0, stream>>>(h, ln1g + l * 1024, ln1b + l * 1024, hb, 1);
        gemm_k<1><<<dim3(32, 128), 256, 0, stream>>>(hb, w1b, b1 + l * 4096, ffn16, nullptr, MS, 4096, 1024);
        gemm_k<2><<<dim3(8, 128), 256, 0, stream>>>(ffn16, w2b, b2 + l * 1024, nullptr, h, MS, 1024, 4096);
        ln_k<<<MS, 256, 0, stream>>>(h, ln2g + l * 1024, ln2b + l * 1024, hb, 1);
    }

    ln_k<<<MS, 256, 0, stream>>>(h, lnog, lnob, hb, 0);
    pool_k<<<BATCH, 256, 0, stream>>>(h, pooled);
    head_k<<<BATCH, 64, 0, stream>>>(pooled, pw, pb, vw, vb, out);
}

// Round 3
// 6137.582 us; speedup vs baseline: 1.2110x; 1.0527x over previous
//
#include <hip/hip_runtime.h>
#include <math.h>

typedef _Float16 f16;
typedef _Float16 f16x8 __attribute__((ext_vector_type(8)));
typedef _Float16 f16x4 __attribute__((ext_vector_type(4)));
typedef float floatx4 __attribute__((ext_vector_type(4)));

#define BATCH 256
#define SEQ 64
#define DMODEL 1024
#define NHEAD 16
#define HDIM 64
#define VOCAB 64
#define DFF 4096
#define NLAYER 8
#define MS (BATCH*SEQ)   // 16384 rows

#define GPTR(p) ((const __attribute__((address_space(1))) void*)(p))
#define LPTR(p) ((__attribute__((address_space(3))) void*)(p))

__device__ __forceinline__ floatx4 mfma16(f16x8 a, f16x8 b, floatx4 c) {
    return __builtin_amdgcn_mfma_f32_16x16x32_f16(a, b, c, 0, 0, 0);
}

__device__ __forceinline__ float gelu_f(float x) {
    return 0.5f * x * (1.f + erff(x * 0.70710678118654752f));
}

// ---------------- embed ------------------------------------------------------
__global__ __launch_bounds__(256) void embed_k(const int* __restrict__ x, const int* __restrict__ step,
                                               const float* __restrict__ tok, const float* __restrict__ se,
                                               float* __restrict__ h, f16* __restrict__ hb) {
    int row = blockIdx.x;
    int t = threadIdx.x;
    int id = x[row];
    int si = min(max(step[0], 0), 63);
    float4 a = ((const float4*)(tok + (size_t)id * DMODEL))[t];
    float4 b = ((const float4*)(se + (size_t)si * DMODEL))[t];
    float4 o;
    o.x = a.x + b.x; o.y = a.y + b.y; o.z = a.z + b.z; o.w = a.w + b.w;
    ((float4*)(h + (size_t)row * DMODEL))[t] = o;
    f16x4 hv; hv[0] = (f16)o.x; hv[1] = (f16)o.y; hv[2] = (f16)o.z; hv[3] = (f16)o.w;
    ((f16x4*)(hb + (size_t)row * DMODEL))[t] = hv;
}

// ---------------- fp32 -> f16 convert ----------------------------------------
__global__ __launch_bounds__(256) void cvt_k(const float* __restrict__ src, f16* __restrict__ dst, int n4) {
    int i = blockIdx.x * 256 + threadIdx.x;
    if (i < n4) {
        float4 v = ((const float4*)src)[i];
        f16x4 o; o[0] = (f16)v.x; o[1] = (f16)v.y; o[2] = (f16)v.z; o[3] = (f16)v.w;
        ((f16x4*)dst)[i] = o;
    }
}

// ---------------- GEMM: C[M,N] = A[M,K] @ Bw[N,K]^T --------------------------
// 256x256 tile, BK=32, ring-of-3 LDS buffers, counted vmcnt(4), 1 barrier/K-tile.
// 8 waves (2M x 4N), per-wave 128x64 output (acc[8][4]).
// MODE 0: store f16 (bias)  MODE 1: store f16 (bias+gelu)  MODE 2: h += acc+bias (fp32)
template<int MODE>
__global__ __launch_bounds__(512, 2) void gemm_k(const f16* __restrict__ A, const f16* __restrict__ Bw,
                                                 const float* __restrict__ bias,
                                                 f16* __restrict__ Cb, float* __restrict__ Hacc,
                                                 int M, int N, int K) {
    __shared__ f16 smem[49152];   // 3 bufs x (A 256x32 + B 256x32) f16 = 96 KB

    const int tid = threadIdx.x;
    const int lane = tid & 63;
    const int wave = tid >> 6;
    const int wm = wave >> 2, wn = wave & 3;     // 2 x 4 wave grid
    const int lr = lane & 15, lg = lane >> 4;

    // bijective XCD-aware block swizzle (all grids have nwg % 8 == 0)
    const unsigned nx = gridDim.x;
    const unsigned nwg = nx * gridDim.y;
    unsigned flat = blockIdx.y * nx + blockIdx.x;
    flat = (flat & 7u) * (nwg >> 3) + (flat >> 3);
    const int m0 = (int)(flat / nx) * 256;
    const int n0 = (int)(flat % nx) * 256;

    floatx4 acc[8][4] = {};

    // staging: thread t covers tile row t/4, f16 col (t&3)*8; call c adds 128 rows.
    const int srow = tid >> 2;          // 0..127
    const int scol = (tid & 3) * 8;     // 0,8,16,24
    const f16* Asrc = A + (size_t)(m0 + srow) * K + scol;
    const f16* Bsrc = Bw + (size_t)(n0 + srow) * K + scol;
    // LDS dest: wave-uniform base (HW adds lane*16B)
    const int ldsw = wave * 512;        // f16 idx: wave*1024 B

#define STAGE(b, t_) do {                                                              \
    size_t ko = (size_t)(t_) * 32;                                                     \
    f16* La = smem + (b) * 16384 + ldsw;                                               \
    f16* Lb = La + 8192;                                                               \
    __builtin_amdgcn_global_load_lds(GPTR(Asrc + ko),            LPTR(La),        16, 0, 0); \
    __builtin_amdgcn_global_load_lds(GPTR(Asrc + ko + 128 * (size_t)K), LPTR(La + 4096), 16, 0, 0); \
    __builtin_amdgcn_global_load_lds(GPTR(Bsrc + ko),            LPTR(Lb),        16, 0, 0); \
    __builtin_amdgcn_global_load_lds(GPTR(Bsrc + ko + 128 * (size_t)K), LPTR(Lb + 4096), 16, 0, 0); \
} while (0)

    const int NT = K >> 5;
    STAGE(0, 0);
    STAGE(1, 1);

    for (int t = 0; t < NT; ++t) {
        const int b = t % 3;
        if (t + 1 < NT) asm volatile("s_waitcnt vmcnt(4)" ::: "memory");
        else            asm volatile("s_waitcnt vmcnt(0)" ::: "memory");
        asm volatile("s_barrier" ::: "memory");

        const f16* Ab = smem + b * 16384;
        const f16* Bb = Ab + 8192;
        f16x8 af[4], bf[4];
#pragma unroll
        for (int ni = 0; ni < 4; ++ni)
            bf[ni] = *(const f16x8*)(Bb + (wn * 64 + ni * 16 + lr) * 32 + lg * 8);
#pragma unroll
        for (int mi = 0; mi < 4; ++mi)
            af[mi] = *(const f16x8*)(Ab + (wm * 128 + mi * 16 + lr) * 32 + lg * 8);

        if (t + 2 < NT) STAGE((t + 2) % 3, t + 2);

        __builtin_amdgcn_s_setprio(1);
#pragma unroll
        for (int mi = 0; mi < 4; ++mi)
#pragma unroll
            for (int ni = 0; ni < 4; ++ni)
                acc[mi][ni] = mfma16(af[mi], bf[ni], acc[mi][ni]);
        __builtin_amdgcn_s_setprio(0);

#pragma unroll
        for (int mi = 0; mi < 4; ++mi)
            af[mi] = *(const f16x8*)(Ab + (wm * 128 + (mi + 4) * 16 + lr) * 32 + lg * 8);

        __builtin_amdgcn_s_setprio(1);
#pragma unroll
        for (int mi = 0; mi < 4; ++mi)
#pragma unroll
            for (int ni = 0; ni < 4; ++ni)
                acc[mi + 4][ni] = mfma16(af[mi], bf[ni], acc[mi + 4][ni]);
        __builtin_amdgcn_s_setprio(0);
    }
#undef STAGE

    if (MODE == 2) {
#pragma unroll
        for (int ni = 0; ni < 4; ++ni) {
            int cc = n0 + wn * 64 + ni * 16 + lr;
            float bvl = bias[cc];
#pragma unroll
            for (int mi = 0; mi < 8; ++mi)
#pragma unroll
                for (int j = 0; j < 4; ++j) {
                    int rr = m0 + wm * 128 + mi * 16 + lg * 4 + j;
                    float* p = Hacc + (size_t)rr * N + cc;
                    *p += acc[mi][ni][j] + bvl;
                }
        }
    } else {
        __syncthreads();                       // full drain; smem reused as scratch
        float bsv[4];
#pragma unroll
        for (int ni = 0; ni < 4; ++ni) bsv[ni] = bias[n0 + wn * 64 + ni * 16 + lr];
        f16* scr = smem + wave * 4096;         // wave-private 64x64 f16, XOR-swizzled blocks
#pragma unroll
        for (int half = 0; half < 2; ++half) {
#pragma unroll
            for (int mi = 0; mi < 4; ++mi)
#pragma unroll
                for (int ni = 0; ni < 4; ++ni)
#pragma unroll
                    for (int j = 0; j < 4; ++j) {
                        int r = mi * 16 + lg * 4 + j;
                        int c = ni * 16 + lr;
                        float v = acc[half * 4 + mi][ni][j] + bsv[ni];
                        if (MODE == 1) v = gelu_f(v);
                        scr[r * 64 + (((c >> 3) ^ (r & 7)) * 8) + (c & 7)] = (f16)v;
                    }
            __syncthreads();
            int gr = m0 + wm * 128 + half * 64 + lane;
            f16* dst = Cb + (size_t)gr * N + n0 + wn * 64;
#pragma unroll
            for (int i = 0; i < 8; ++i) {
                f16x8 v = *(const f16x8*)(scr + lane * 64 + ((i ^ (lane & 7)) * 8));
                *(f16x8*)(dst + i * 8) = v;
            }
            __syncthreads();
        }
    }
}

// ---------------- attention: one wave per (b,h) -------------------------------
__global__ __launch_bounds__(64) void attn_k(const f16* __restrict__ qkv, const float* __restrict__ rb,
                                             f16* __restrict__ ctx) {
    const int hh = blockIdx.x;
    const int bb = blockIdx.y;
    const int lane = threadIdx.x;
    __shared__ float rbs[128];
    __shared__ f16 Vt[64][72];
    __shared__ f16 Pl[64][72];

    for (int i = lane; i < 127; i += 64) rbs[i] = rb[i];

    const f16* vrow = qkv + (size_t)(bb * 64 + lane) * 3072 + 2048 + hh * 64;
#pragma unroll
    for (int i = 0; i < 8; ++i) {
        f16x8 v = *(const f16x8*)(vrow + i * 8);
#pragma unroll
        for (int j = 0; j < 8; ++j) Vt[i * 8 + j][lane] = v[j];
    }
    __syncthreads();

    const int lr = lane & 15, lg = lane >> 4;
    floatx4 sacc[4][4] = {};
    const f16* qbase = qkv + (size_t)(bb * 64) * 3072 + hh * 64;
#pragma unroll
    for (int kk = 0; kk < 64; kk += 32) {
        f16x8 qa[4], kb[4];
#pragma unroll
        for (int mf = 0; mf < 4; ++mf)
            qa[mf] = *(const f16x8*)(qbase + (size_t)(mf * 16 + lr) * 3072 + kk + lg * 8);
#pragma unroll
        for (int nf = 0; nf < 4; ++nf)
            kb[nf] = *(const f16x8*)(qbase + 1024 + (size_t)(nf * 16 + lr) * 3072 + kk + lg * 8);
#pragma unroll
        for (int mf = 0; mf < 4; ++mf)
#pragma unroll
            for (int nf = 0; nf < 4; ++nf)
                sacc[mf][nf] = mfma16(qa[mf], kb[nf], sacc[mf][nf]);
    }

#pragma unroll
    for (int mf = 0; mf < 4; ++mf) {
#pragma unroll
        for (int j = 0; j < 4; ++j) {
            int qrow = mf * 16 + lg * 4 + j;
            float v0 = sacc[mf][0][j] * 0.125f + rbs[qrow - (0  + lr) + 63];
            float v1 = sacc[mf][1][j] * 0.125f + rbs[qrow - (16 + lr) + 63];
            float v2 = sacc[mf][2][j] * 0.125f + rbs[qrow - (32 + lr) + 63];
            float v3 = sacc[mf][3][j] * 0.125f + rbs[qrow - (48 + lr) + 63];
            float mx = fmaxf(fmaxf(v0, v1), fmaxf(v2, v3));
            for (int m = 1; m < 16; m <<= 1) mx = fmaxf(mx, __shfl_xor(mx, m));
            v0 = __expf(v0 - mx); v1 = __expf(v1 - mx); v2 = __expf(v2 - mx); v3 = __expf(v3 - mx);
            float sum = v0 + v1 + v2 + v3;
            for (int m = 1; m < 16; m <<= 1) sum += __shfl_xor(sum, m);
            float inv = 1.f / sum;
            Pl[qrow][0  + lr] = (f16)(v0 * inv);
            Pl[qrow][16 + lr] = (f16)(v1 * inv);
            Pl[qrow][32 + lr] = (f16)(v2 * inv);
            Pl[qrow][48 + lr] = (f16)(v3 * inv);
        }
    }
    __syncthreads();

    floatx4 oacc[4][4] = {};
#pragma unroll
    for (int kk = 0; kk < 64; kk += 32) {
        f16x8 pa[4], vb[4];
#pragma unroll
        for (int mf = 0; mf < 4; ++mf) pa[mf] = *(const f16x8*)&Pl[mf * 16 + lr][kk + lg * 8];
#pragma unroll
        for (int nf = 0; nf < 4; ++nf) vb[nf] = *(const f16x8*)&Vt[nf * 16 + lr][kk + lg * 8];
#pragma unroll
        for (int mf = 0; mf < 4; ++mf)
#pragma unroll
            for (int nf = 0; nf < 4; ++nf)
                oacc[mf][nf] = mfma16(pa[mf], vb[nf], oacc[mf][nf]);
    }
    __syncthreads();
#pragma unroll
    for (int mf = 0; mf < 4; ++mf)
#pragma unroll
        for (int nf = 0; nf < 4; ++nf)
#pragma unroll
            for (int j = 0; j < 4; ++j)
                Pl[mf * 16 + lg * 4 + j][nf * 16 + lr] = (f16)oacc[mf][nf][j];
    __syncthreads();
    f16* crow = ctx + (size_t)(bb * 64 + lane) * DMODEL + hh * 64;
#pragma unroll
    for (int i = 0; i < 8; ++i) {
        f16x8 v = *(const f16x8*)&Pl[lane][i * 8];
        *(f16x8*)(crow + i * 8) = v;
    }
}

// ---------------- LayerNorm in-place on h, optionally emit f16 copy -----------
__global__ __launch_bounds__(256) void ln_k(float* __restrict__ h, const float* __restrict__ g,
                                            const float* __restrict__ b, f16* __restrict__ hb, int emit) {
    int row = blockIdx.x;
    int t = threadIdx.x;
    float4 v = ((const float4*)(h + (size_t)row * DMODEL))[t];
    float s = v.x + v.y + v.z + v.w;
    float ss = v.x * v.x + v.y * v.y + v.z * v.z + v.w * v.w;
    for (int m = 1; m < 64; m <<= 1) { s += __shfl_xor(s, m); ss += __shfl_xor(ss, m); }
    __shared__ float red[8];
    if ((t & 63) == 0) { red[(t >> 6) * 2] = s; red[(t >> 6) * 2 + 1] = ss; }
    __syncthreads();
    s = red[0] + red[2] + red[4] + red[6];
    ss = red[1] + red[3] + red[5] + red[7];
    float mean = s * (1.f / 1024.f);
    float var = ss * (1.f / 1024.f) - mean * mean;
    float rstd = rsqrtf(var + 1e-5f);
    float4 gg = ((const float4*)g)[t];
    float4 bb = ((const float4*)b)[t];
    float4 o;
    o.x = (v.x - mean) * rstd * gg.x + bb.x;
    o.y = (v.y - mean) * rstd * gg.y + bb.y;
    o.z = (v.z - mean) * rstd * gg.z + bb.z;
    o.w = (v.w - mean) * rstd * gg.w + bb.w;
    ((float4*)(h + (size_t)row * DMODEL))[t] = o;
    if (emit) {
        f16x4 hv; hv[0] = (f16)o.x; hv[1] = (f16)o.y; hv[2] = (f16)o.z; hv[3] = (f16)o.w;
        ((f16x4*)(hb + (size_t)row * DMODEL))[t] = hv;
    }
}

// ---------------- mean over S -------------------------------------------------
__global__ __launch_bounds__(256) void pool_k(const float* __restrict__ h, float* __restrict__ pooled) {
    int b = blockIdx.x;
    int t = threadIdx.x;
    float sx = 0, sy = 0, sz = 0, sw = 0;
    for (int s = 0; s < SEQ; ++s) {
        float4 v = ((const float4*)(h + (size_t)(b * SEQ + s) * DMODEL))[t];
        sx += v.x; sy += v.y; sz += v.z; sw += v.w;
    }
    float4 o; o.x = sx * (1.f / 64.f); o.y = sy * (1.f / 64.f); o.z = sz * (1.f / 64.f); o.w = sw * (1.f / 64.f);
    ((float4*)(pooled + (size_t)b * DMODEL))[t] = o;
}

// ---------------- policy / value heads ---------------------------------------
__global__ __launch_bounds__(64) void head_k(const float* __restrict__ pooled, const float* __restrict__ pw,
                                             const float* __restrict__ pb, const float* __restrict__ vw,
                                             const float* __restrict__ vb, float* __restrict__ out) {
    int b = blockIdx.x;
    int lane = threadIdx.x;
    const float* pr = pooled + (size_t)b * DMODEL;
    const float* wr = pw + (size_t)lane * DMODEL;
    float accp = 0.f;
    for (int d = 0; d < DMODEL; d += 4) {
        float4 x = *(const float4*)(pr + d);
        float4 w = *(const float4*)(wr + d);
        accp += x.x * w.x + x.y * w.y + x.z * w.z + x.w * w.w;
    }
    float accv = 0.f;
    for (int d = lane * 4; d < DMODEL; d += 256) {
        float4 x = *(const float4*)(pr + d);
        float4 w = *(const float4*)(vw + d);
        accv += x.x * w.x + x.y * w.y + x.z * w.z + x.w * w.w;
    }
    for (int m = 1; m < 64; m <<= 1) accv += __shfl_xor(accv, m);
    out[b * VOCAB + lane] = accp + pb[lane];
    if (lane == 0) out[BATCH * VOCAB + b] = accv + vb[0];
}

extern "C" void kernel_launch(void* const* d_in, const int* in_sizes, int n_in,
                              void* d_out, int out_size, void* d_ws, size_t ws_size,
                              hipStream_t stream) {
    const int*   x      = (const int*)d_in[0];
    const int*   step   = (const int*)d_in[1];
    const float* tok    = (const float*)d_in[2];
    const float* se     = (const float*)d_in[3];
    const float* qkv_w  = (const float*)d_in[4];
    const float* qkv_b  = (const float*)d_in[5];
    const float* out_w  = (const float*)d_in[6];
    const float* out_b  = (const float*)d_in[7];
    const float* relb   = (const float*)d_in[8];
    const float* w1     = (const float*)d_in[9];
    const float* b1     = (const float*)d_in[10];
    const float* w2     = (const float*)d_in[11];
    const float* b2     = (const float*)d_in[12];
    const float* ln1g   = (const float*)d_in[13];
    const float* ln1b   = (const float*)d_in[14];
    const float* ln2g   = (const float*)d_in[15];
    const float* ln2b   = (const float*)d_in[16];
    const float* lnog   = (const float*)d_in[17];
    const float* lnob   = (const float*)d_in[18];
    const float* pw     = (const float*)d_in[19];
    const float* pb     = (const float*)d_in[20];
    const float* vw     = (const float*)d_in[21];
    const float* vb     = (const float*)d_in[22];

    float* out = (float*)d_out;
    float* h = out + BATCH * VOCAB + BATCH;       // h region: [16384,1024] fp32

    char* ws = (char*)d_ws;
    f16* hb     = (f16*)(ws);                                  // 33,554,432 B
    f16* uni    = (f16*)(ws + 33554432);                       // qkv16 / ffn16 union
    f16* qkv16  = uni;
    f16* ffn16  = uni;
    f16* ctx16  = (f16*)(ws + 167772160);
    f16* wqb    = (f16*)(ws + 201326592);
    f16* wob    = (f16*)(ws + 207618048);
    f16* w1b    = (f16*)(ws + 209715200);
    f16* w2b    = (f16*)(ws + 218103808);
    float* pooled = (float*)(ws + 226492416);

    embed_k<<<MS, 256, 0, stream>>>(x, step, tok, se, h, hb);

    for (int l = 0; l < NLAYER; ++l) {
        cvt_k<<<3072, 256, 0, stream>>>(qkv_w + (size_t)l * 3145728, wqb, 786432);
        cvt_k<<<1024, 256, 0, stream>>>(out_w + (size_t)l * 1048576, wob, 262144);
        cvt_k<<<4096, 256, 0, stream>>>(w1 + (size_t)l * 4194304, w1b, 1048576);
        cvt_k<<<4096, 256, 0, stream>>>(w2 + (size_t)l * 4194304, w2b, 1048576);

        gemm_k<0><<<dim3(12, 64), 512, 0, stream>>>(hb, wqb, qkv_b + l * 3072, qkv16, nullptr, MS, 3072, 1024);
        attn_k<<<dim3(NHEAD, BATCH), 64, 0, stream>>>(qkv16, relb + l * 127, ctx16);
        gemm_k<2><<<dim3(4, 64), 512, 0, stream>>>(ctx16, wob, out_b + l * 1024, nullptr, h, MS, 1024, 1024);
        ln_k<<<MS, 256, 0, stream>>>(h, ln1g + l * 1024, ln1b + l * 1024, hb, 1);
        gemm_k<1><<<dim3(16, 64), 512, 0, stream>>>(hb, w1b, b1 + l * 4096, ffn16, nullptr, MS, 4096, 1024);
        gemm_k<2><<<dim3(4, 64), 512, 0, stream>>>(ffn16, w2b, b2 + l * 1024, nullptr, h, MS, 1024, 4096);
        ln_k<<<MS, 256, 0, stream>>>(h, ln2g + l * 1024, ln2b + l * 1024, hb, 1);
    }

    ln_k<<<MS, 256, 0, stream>>>(h, lnog, lnob, hb, 0);
    pool_k<<<BATCH, 256, 0, stream>>>(h, pooled);
    head_k<<<BATCH, 64, 0, stream>>>(pooled, pw, pb, vw, vb, out);
}